// Round 2
// baseline (686.816 us; speedup 1.0000x reference)
//
#include <hip/hip_runtime.h>
#include <hip/hip_bf16.h>
#include <cstdint>

// FM forward: out = sigmoid(x@w + w0 + 0.5*(sum_k (x@bw)_k^2 - sum_j x~_j^2 * s~_j))
// B=262144, F=512, K=64. x,bw split into bf16 hi+lo (RNE); xv via 3 MFMAs
// (hi*hi + hi*lo + lo*hi) 16x16x32; s~_j = sum_k b~_jk^2 precomputed per block.
// NO d_ws usage (round-1 failure: OOB workspace writes corrupted pristine inputs).
// 1024-thread blocks (16 waves, 4/SIMD), 1 rowtile (16 rows) per wave, 2 groups.

#define F_DIM 512

typedef __attribute__((ext_vector_type(8))) short bf16x8;   // 8 bf16 = 4 VGPRs
typedef __attribute__((ext_vector_type(4))) float f32x4;

union FragU { uint32_t u[4]; uint4 q; bf16x8 v; };

// pack 2 floats -> 2 bf16 (RNE), low16 = a, high16 = b  (v_cvt_pk_bf16_f32)
__device__ __forceinline__ uint32_t pk_bf16(float a, float b) {
    __hip_bfloat162 h = __float22bfloat162_rn(float2{a, b});
    union { __hip_bfloat162 h2; uint32_t u; } cv; cv.h2 = h;
    return cv.u;
}

// split one float into hi/lo bf16 bit patterns + reconstructed x~ = hi+lo
__device__ __forceinline__ void split1(float fv, uint32_t& th, uint32_t& tl, float& xt) {
    uint32_t hp = pk_bf16(fv, fv);
    th = hp & 0xFFFFu;
    float fh = __uint_as_float(hp << 16);
    float r  = fv - fh;                       // exact in fp32
    uint32_t lp = pk_bf16(r, r);
    tl = lp & 0xFFFFu;
    float fl = __uint_as_float(lp << 16);
    xt = fh + fl;
}

// Convert 8 fp32 x-values into hi/lo bf16 A-fragments; accumulate lin & tt terms.
__device__ __forceinline__ void conv8(const float4& A, const float4& Bv,
                                      const float4& wv0, const float4& wv1,
                                      const float4& sv0, const float4& sv1,
                                      FragU& H, FragU& L, float& lin, float& tt) {
    float f[8]  = {A.x, A.y, A.z, A.w, Bv.x, Bv.y, Bv.z, Bv.w};
    float wv[8] = {wv0.x, wv0.y, wv0.z, wv0.w, wv1.x, wv1.y, wv1.z, wv1.w};
    float sv[8] = {sv0.x, sv0.y, sv0.z, sv0.w, sv1.x, sv1.y, sv1.z, sv1.w};
    #pragma unroll
    for (int i = 0; i < 4; ++i) {
        float f0 = f[2 * i], f1 = f[2 * i + 1];
        uint32_t hp = pk_bf16(f0, f1);
        H.u[i] = hp;
        float fh0 = __uint_as_float(hp << 16);
        float fh1 = __uint_as_float(hp & 0xFFFF0000u);
        float r0 = f0 - fh0, r1 = f1 - fh1;
        uint32_t lp = pk_bf16(r0, r1);
        L.u[i] = lp;
        float fl0 = __uint_as_float(lp << 16);
        float fl1 = __uint_as_float(lp & 0xFFFF0000u);
        float xt0 = fh0 + fl0, xt1 = fh1 + fl1;
        tt  = fmaf(xt0 * xt0, sv[2 * i],     tt);
        tt  = fmaf(xt1 * xt1, sv[2 * i + 1], tt);
        lin = fmaf(f0, wv[2 * i],     lin);
        lin = fmaf(f1, wv[2 * i + 1], lin);
    }
}

// 1024 threads = 16 waves = 4 waves/SIMD, 1 block/CU (132KB LDS).
// Wave handles 16 rows per group, 2 groups -> block covers 512 contiguous rows.
// Grid 512 -> 262144 rows.
__global__ __launch_bounds__(1024, 4) void fm_main(
    const float* __restrict__ x, const float* __restrict__ w0p,
    const float* __restrict__ w, const float* __restrict__ bw,
    float* __restrict__ out)
{
    extern __shared__ unsigned char smem_raw[];
    uint4* lds_b = (uint4*)smem_raw;                 // [0,4096)=hi frags, [4096,8192)=lo
    float* lds_w = (float*)(smem_raw + 131072);      // 512 f32
    float* lds_s = lds_w + 512;                      // 512 f32

    // ---- Prologue: pack bw into per-lane MFMA B-fragment layout (16x16x32 bf16)
    // frag t = (kc*4+nt)*64 + lane ; lane holds B[k=kc*32+(lane>>4)*8+j][n=nt*16+(lane&15)]
    for (int t = threadIdx.x; t < 4096; t += 1024) {
        const int Lq = t & 63, nt = (t >> 6) & 3, kc = t >> 8;
        const int n  = nt * 16 + (Lq & 15);
        const int kb = kc * 32 + ((Lq >> 4) * 8);
        uint32_t hh[8], ll[8]; float dmy;
        #pragma unroll
        for (int j = 0; j < 8; ++j)
            split1(bw[(kb + j) * 64 + n], hh[j], ll[j], dmy);
        uint4 Hq, Lo;
        Hq.x = hh[0] | (hh[1] << 16); Hq.y = hh[2] | (hh[3] << 16);
        Hq.z = hh[4] | (hh[5] << 16); Hq.w = hh[6] | (hh[7] << 16);
        Lo.x = ll[0] | (ll[1] << 16); Lo.y = ll[2] | (ll[3] << 16);
        Lo.z = ll[4] | (ll[5] << 16); Lo.w = ll[6] | (ll[7] << 16);
        lds_b[t] = Hq;
        lds_b[4096 + t] = Lo;
    }
    // s~_j = sum_k (split(bw[j][k]))^2  (consistent with MFMA operand values); w -> LDS
    if (threadIdx.x < 512) {
        const int j = threadIdx.x;
        float s = 0.f;
        for (int k = 0; k < 64; ++k) {
            uint32_t a, b; float bt;
            split1(bw[j * 64 + k], a, b, bt);
            s = fmaf(bt, bt, s);
        }
        lds_s[j] = s;
    } else {
        lds_w[threadIdx.x - 512] = w[threadIdx.x - 512];
    }
    __syncthreads();

    const int lane = threadIdx.x & 63;
    const int wave = threadIdx.x >> 6;     // 0..15
    const int quad = lane >> 4;
    const int l15  = lane & 15;
    const int koff = quad * 8;
    const float w0v = w0p[0];

    for (int grp = 0; grp < 2; ++grp) {
        const size_t rowbase = ((size_t)blockIdx.x * 2 + grp) * 256 + (size_t)wave * 16;
        const float* p = x + (rowbase + l15) * F_DIM + koff;

        f32x4 acc[4];
        #pragma unroll
        for (int nt = 0; nt < 4; ++nt) acc[nt] = (f32x4){0.f, 0.f, 0.f, 0.f};
        float lin = 0.f, tt = 0.f;

        float4 c0 = *(const float4*)(p);
        float4 c1 = *(const float4*)(p + 4);

        #pragma unroll 2
        for (int kc = 0; kc < 16; ++kc) {
            const int kn = (kc + 1) & 15;              // wrap: last prefetch harmless
            float4 n0 = *(const float4*)(p + kn * 32);
            float4 n1 = *(const float4*)(p + kn * 32 + 4);

            const float4 wv0 = *(const float4*)(lds_w + kc * 32 + koff);
            const float4 wv1 = *(const float4*)(lds_w + kc * 32 + koff + 4);
            const float4 sv0 = *(const float4*)(lds_s + kc * 32 + koff);
            const float4 sv1 = *(const float4*)(lds_s + kc * 32 + koff + 4);

            FragU ah, al;
            conv8(c0, c1, wv0, wv1, sv0, sv1, ah, al, lin, tt);

            #pragma unroll
            for (int nt = 0; nt < 4; ++nt) {
                FragU bh, bl;
                const int fi = (kc * 4 + nt) * 64 + lane;
                bh.q = lds_b[fi];
                bl.q = lds_b[4096 + fi];
                acc[nt] = __builtin_amdgcn_mfma_f32_16x16x32_bf16(ah.v, bh.v, acc[nt], 0, 0, 0);
                acc[nt] = __builtin_amdgcn_mfma_f32_16x16x32_bf16(ah.v, bl.v, acc[nt], 0, 0, 0);
                acc[nt] = __builtin_amdgcn_mfma_f32_16x16x32_bf16(al.v, bh.v, acc[nt], 0, 0, 0);
            }
            c0 = n0; c1 = n1;
        }

        // ---- epilogue ----
        // C/D layout (verified): D[row = quad*4 + r][col = nt*16 + l15] in acc[nt][r].
        float pa[4];
        #pragma unroll
        for (int r = 0; r < 4; ++r) {
            pa[r] = acc[0][r] * acc[0][r];
            pa[r] = fmaf(acc[1][r], acc[1][r], pa[r]);
            pa[r] = fmaf(acc[2][r], acc[2][r], pa[r]);
            pa[r] = fmaf(acc[3][r], acc[3][r], pa[r]);
        }
        #pragma unroll
        for (int m = 1; m <= 8; m <<= 1) {
            #pragma unroll
            for (int r = 0; r < 4; ++r) pa[r] += __shfl_xor(pa[r], m, 64);
        }
        // lin/tt: lane covers row l15, k-subset of its quad -> reduce across quads
        lin += __shfl_xor(lin, 16, 64); lin += __shfl_xor(lin, 32, 64);
        tt  += __shfl_xor(tt, 16, 64);  tt  += __shfl_xor(tt, 32, 64);

        // sq for row16 = l15 lives in quad (l15>>2), reg (l15&3); all lanes of that
        // quad hold the reduced value -> gather from lane ((l15>>2)<<4).
        const int src = (l15 >> 2) << 4;
        float g[4];
        #pragma unroll
        for (int r = 0; r < 4; ++r) g[r] = __shfl(pa[r], src, 64);
        float s01 = (l15 & 1) ? g[1] : g[0];
        float s23 = (l15 & 1) ? g[3] : g[2];
        float sq  = (l15 & 2) ? s23 : s01;

        float a = lin + w0v + 0.5f * (sq - tt);
        float o = 1.0f / (1.0f + __expf(-a));
        if (lane < 16) out[rowbase + lane] = o;
    }
}

extern "C" void kernel_launch(void* const* d_in, const int* in_sizes, int n_in,
                              void* d_out, int out_size, void* d_ws, size_t ws_size,
                              hipStream_t stream) {
    const float* x  = (const float*)d_in[0];
    const float* w0 = (const float*)d_in[1];
    const float* w  = (const float*)d_in[2];
    const float* bw = (const float*)d_in[3];
    float* out = (float*)d_out;
    (void)d_ws; (void)ws_size;   // deliberately unused (round-1 OOB corruption)

    (void)hipFuncSetAttribute((const void*)fm_main,
                              hipFuncAttributeMaxDynamicSharedMemorySize, 135168);
    fm_main<<<512, 1024, 135168, stream>>>(x, w0, w, bw, out);
}